// Round 2
// baseline (18.429 us; speedup 1.0000x reference)
//
#include <hip/hip_runtime.h>

// StatisticalSMA: out[b, t, c] = 96-step SMA recurrence on the last 5
// timesteps of x[b, :, c].  The recurrence is linear, so each output is a
// fixed linear combination of the 5 initial window values:
//     f_t = sum_i COEF[t][i] * w_i
// The 96x5 coefficient table is computed at compile time (double precision).
// This breaks the serial dependence chain -> t can be parallelized.
//
// Launch: one block per batch b (2048 blocks x 256 threads).
//   lane (threadIdx&63) = channel  -> every load/store is 256 B contiguous
//   wave (threadIdx>>6) = t-quartile (24 t's each)
// => 8192 waves = 32 waves/CU (max occupancy). Window reads are 4x redundant
// within a block but L1-cached; HBM traffic stays ~53 MB total.

#define SMA_B 2048
#define SMA_S 512
#define SMA_C 64
#define SMA_W 5
#define SMA_T 96
#define TPG   24   // t's per wave (96 / 4 waves)

struct CoefTable { float c[SMA_T][SMA_W]; };

constexpr CoefTable make_table() {
    CoefTable t{};
    // w[i][j] = coefficient of initial value j in current window slot i
    double w[SMA_W][SMA_W] = {};
    for (int i = 0; i < SMA_W; ++i) w[i][i] = 1.0;
    for (int s = 0; s < SMA_T; ++s) {
        double f[SMA_W];
        for (int j = 0; j < SMA_W; ++j) {
            double acc = 0.0;
            for (int i = 0; i < SMA_W; ++i) acc += w[i][j];
            f[j] = acc * 0.2;
        }
        for (int j = 0; j < SMA_W; ++j) t.c[s][j] = (float)f[j];
        for (int i = 0; i < SMA_W - 1; ++i)
            for (int j = 0; j < SMA_W; ++j) w[i][j] = w[i + 1][j];
        for (int j = 0; j < SMA_W; ++j) w[SMA_W - 1][j] = f[j];
    }
    return t;
}

constexpr CoefTable kCoef = make_table();
__constant__ CoefTable COEF = kCoef;

__global__ __launch_bounds__(256) void StatisticalSMA_kernel(
    const float* __restrict__ x, float* __restrict__ out) {
    const int b  = blockIdx.x;          // batch
    const int c  = threadIdx.x & 63;    // channel == lane
    const int wg = threadIdx.x >> 6;    // wave index == t-quartile (uniform per wave)

    // initial window: x[b, S-W .. S-1, c]
    const float* xp = x + (size_t)b * (SMA_S * SMA_C) + (SMA_S - SMA_W) * SMA_C + c;
    const float w0 = xp[0 * SMA_C];
    const float w1 = xp[1 * SMA_C];
    const float w2 = xp[2 * SMA_C];
    const float w3 = xp[3 * SMA_C];
    const float w4 = xp[4 * SMA_C];

    float* op = out + (size_t)b * (SMA_T * SMA_C) + (size_t)(wg * TPG) * SMA_C + c;
    #pragma unroll
    for (int tt = 0; tt < TPG; ++tt) {
        const float* cf = COEF.c[wg * TPG + tt];   // wave-uniform -> s_load
        float f = w0 * cf[0] + w1 * cf[1] + w2 * cf[2] + w3 * cf[3] + w4 * cf[4];
        op[tt * SMA_C] = f;
    }
}

extern "C" void kernel_launch(void* const* d_in, const int* in_sizes, int n_in,
                              void* d_out, int out_size, void* d_ws, size_t ws_size,
                              hipStream_t stream) {
    const float* x = (const float*)d_in[0];
    float* out = (float*)d_out;
    StatisticalSMA_kernel<<<SMA_B, 256, 0, stream>>>(x, out);
}

// Round 3
// 14.445 us; speedup vs baseline: 1.2758x; 1.2758x over previous
//
#include <hip/hip_runtime.h>

// StatisticalSMA v3: out[b,t,c], t<96, from 96-step SMA recurrence on the
// last 5 timesteps of x[b,:,c].
//
// Structure:
//  - t split into 4 chunks of 24. Chunk id = wave id, forced into an SGPR via
//    readfirstlane and dispatched through a UNIFORM switch to run_chunk<Q>,
//    so the chunk-start window (a fixed linear combo of the 5 initial values,
//    constexpr 5x5 table) folds to FMA literals. Inside the chunk the plain
//    serial recurrence runs with immediate 0.2f. Zero coefficient memory
//    traffic (R2's per-lane COEF vloads were the regression cause).
//  - Each lane owns 4 channels (float4): lane&15 = col group, lane>>4 =
//    batch subgroup; block = 4 batches x 4 waves. All loads/stores are
//    256B-segment coalesced dwordx4.
//  - 512 blocks x 256 thr = 2048 waves = 8 waves/CU; 24 dwordx4 stores/thread.

#define SMA_B 2048
#define SMA_S 512
#define SMA_C 64
#define SMA_W 5
#define SMA_T 96
#define NCHUNK 4
#define TPC 24   // timesteps per chunk

struct ChunkWin { float c[NCHUNK][SMA_W][SMA_W]; };

// cw[q][i][j] = coefficient of initial window value j in window slot i at
// the start of chunk q (i.e. after q*TPC recurrence steps). Double precision.
constexpr ChunkWin make_cw() {
    ChunkWin out{};
    double w[SMA_W][SMA_W] = {};
    for (int i = 0; i < SMA_W; ++i) w[i][i] = 1.0;
    for (int q = 0; q < NCHUNK; ++q) {
        for (int i = 0; i < SMA_W; ++i)
            for (int j = 0; j < SMA_W; ++j) out.c[q][i][j] = (float)w[i][j];
        for (int s = 0; s < TPC; ++s) {
            double f[SMA_W];
            for (int j = 0; j < SMA_W; ++j) {
                double a = 0.0;
                for (int i = 0; i < SMA_W; ++i) a += w[i][j];
                f[j] = a * 0.2;
            }
            for (int i = 0; i + 1 < SMA_W; ++i)
                for (int j = 0; j < SMA_W; ++j) w[i][j] = w[i + 1][j];
            for (int j = 0; j < SMA_W; ++j) w[SMA_W - 1][j] = f[j];
        }
    }
    return out;
}
constexpr ChunkWin kCW = make_cw();

template <int Q>
__device__ __forceinline__ void run_chunk(const float4 (&w)[SMA_W],
                                          float* __restrict__ op) {
    // chunk-start window: v[i] = sum_j kCW.c[Q][i][j] * w[j]
    // (constexpr table -> after unroll all coefs are literals; 0/1 fold away)
    float4 v[SMA_W];
    #pragma unroll
    for (int i = 0; i < SMA_W; ++i) {
        float ax = 0.f, ay = 0.f, az = 0.f, aw = 0.f;
        bool first = true;
        #pragma unroll
        for (int j = 0; j < SMA_W; ++j) {
            const float cj = kCW.c[Q][i][j];   // compile-time constant
            if (cj == 0.0f) continue;          // folds at -O3
            if (first) {
                ax = cj * w[j].x; ay = cj * w[j].y;
                az = cj * w[j].z; aw = cj * w[j].w;
                first = false;
            } else {
                ax += cj * w[j].x; ay += cj * w[j].y;
                az += cj * w[j].z; aw += cj * w[j].w;
            }
        }
        v[i] = make_float4(ax, ay, az, aw);
    }
    #pragma unroll
    for (int t = 0; t < TPC; ++t) {
        float4 f;
        f.x = (v[0].x + v[1].x + v[2].x + v[3].x + v[4].x) * 0.2f;
        f.y = (v[0].y + v[1].y + v[2].y + v[3].y + v[4].y) * 0.2f;
        f.z = (v[0].z + v[1].z + v[2].z + v[3].z + v[4].z) * 0.2f;
        f.w = (v[0].w + v[1].w + v[2].w + v[3].w + v[4].w) * 0.2f;
        *reinterpret_cast<float4*>(op + t * SMA_C) = f;
        v[0] = v[1]; v[1] = v[2]; v[2] = v[3]; v[3] = v[4]; v[4] = f;
    }
}

__global__ __launch_bounds__(256) void StatisticalSMA_kernel(
    const float* __restrict__ x, float* __restrict__ out) {
    const int lane = threadIdx.x & 63;
    // wave id == t-chunk; readfirstlane forces SGPR -> uniform branch
    const int q    = __builtin_amdgcn_readfirstlane((int)(threadIdx.x >> 6));
    const int colg = lane & 15;        // float4 column group (channels colg*4..+3)
    const int bsub = lane >> 4;        // batch subgroup 0..3
    const int b    = blockIdx.x * 4 + bsub;

    // initial window: x[b, S-W .. S-1, colg*4 .. colg*4+3]
    const float* xp = x + (size_t)b * (SMA_S * SMA_C)
                        + (SMA_S - SMA_W) * SMA_C + colg * 4;
    float4 w[SMA_W];
    #pragma unroll
    for (int i = 0; i < SMA_W; ++i)
        w[i] = *reinterpret_cast<const float4*>(xp + i * SMA_C);

    float* op = out + (size_t)b * (SMA_T * SMA_C)
                    + (size_t)(q * TPC) * SMA_C + colg * 4;
    switch (q) {
        case 0: run_chunk<0>(w, op); break;
        case 1: run_chunk<1>(w, op); break;
        case 2: run_chunk<2>(w, op); break;
        default: run_chunk<3>(w, op); break;
    }
}

extern "C" void kernel_launch(void* const* d_in, const int* in_sizes, int n_in,
                              void* d_out, int out_size, void* d_ws, size_t ws_size,
                              hipStream_t stream) {
    const float* x = (const float*)d_in[0];
    float* out = (float*)d_out;
    StatisticalSMA_kernel<<<SMA_B / 4, 256, 0, stream>>>(x, out);
}